// Round 12
// baseline (243.769 us; speedup 1.0000x reference)
//
#include <hip/hip_runtime.h>
#include <hip/hip_bf16.h>

// sinogram: [1,16,360,736] f32, grid: [1,360,16384,2] f32,
// square_inv: [1,1,360,16384] f32, out: [1,16,16384] f32
#define NP 16384
#define NV 360
#define ND 736
#define NC 16
#define VS 8                 // view chunks of 45

__device__ __forceinline__ float bf_lo(uint u) { return __uint_as_float(u << 16); }
__device__ __forceinline__ float bf_hi(uint u) { return __uint_as_float(u & 0xffff0000u); }

// K0: transpose+quantize sino [C][H*W] f32 -> [H*W][16ch] bf16, with the
// reference's *1000 folded into the table (identical relative bf16 error).
// 32B corners: a quad's row-pair {x0,x1} spans <=2 64B lines. Fused out-zero.
__global__ __launch_bounds__(256) void k0_transpose(const float* __restrict__ sino,
                                                    ushort* __restrict__ st,
                                                    float* __restrict__ out) {
    int idx = blockIdx.x * 256 + threadIdx.x;   // idx = y*ND + x
    if (idx < NC * NP) out[idx] = 0.0f;         // 262144 <= 264960 threads
    if (idx >= NV * ND) return;
    uint packed[8];
#pragma unroll
    for (int q = 0; q < 8; ++q) {
        uint ul = __float_as_uint(sino[(2 * q)     * (NV * ND) + idx] * 1000.0f);
        uint uh = __float_as_uint(sino[(2 * q + 1) * (NV * ND) + idx] * 1000.0f);
        // round-to-nearest-even bf16
        ul = (ul + 0x7fffu + ((ul >> 16) & 1u)) >> 16;
        uh = (uh + 0x7fffu + ((uh >> 16) & 1u)) >> 16;
        packed[q] = ul | (uh << 16);
    }
    uint4* dst = reinterpret_cast<uint4*>(st + ((size_t)idx << 4));
    dst[0] = make_uint4(packed[0], packed[1], packed[2], packed[3]);
    dst[1] = make_uint4(packed[4], packed[5], packed[6], packed[7]);
}

// Backproj: lane QUADS own one pixel (sub = {x-side, ch-half}), R11 layout.
// NEW: views processed in explicit groups of 3 — all 6 gathers + 3 stream
// loads issue before any FMA consumes them (forces MLP; R11's VGPR=20 showed
// the compiler was serializing gathers). __launch_bounds__(256,8) keeps
// 8 blocks/CU (VGPR<=64).
__global__ __launch_bounds__(256, 8) void backproj(const float* __restrict__ grd,
                                                   const float* __restrict__ sq,
                                                   const ushort* __restrict__ st,
                                                   float* __restrict__ out) {
    int tid  = threadIdx.x;
    int p    = ((blockIdx.x & 255) << 6) + (tid >> 2);   // 64 pixels per block
    int vs   = blockIdx.x >> 8;
    int sub  = tid & 3;
    int side = sub & 1;          // 0: x0, 1: x1
    int half = sub >> 1;         // 0: ch0-7, 1: ch8-15
    int v0 = vs * (NV / VS);     // 45-view chunks; 45 = 15 groups of 3
    int v1 = v0 + (NV / VS);

    float acc[8];
#pragma unroll
    for (int k = 0; k < 8; ++k) acc[k] = 0.0f;

    const float2* grd2 = reinterpret_cast<const float2*>(grd);
    const uint4*  tbl  = reinterpret_cast<const uint4*>(st);

    for (int v = v0; v < v1; v += 3) {
        uint4 A[3], B[3];
        float WA[3], WB[3];
#pragma unroll
        for (int j = 0; j < 3; ++j) {
            int gi = (v + j) * NP + p;
            float2 g = grd2[gi];             // quad lanes share addr (merges)
            float w  = sq[gi];               // *1000 pre-folded into table

            // unnormalize, align_corners=False (exact reference formula)
            float ix = ((g.x + 1.0f) * (float)ND - 1.0f) * 0.5f;
            float iy = ((g.y + 1.0f) * (float)NV - 1.0f) * 0.5f;
            float x0f = floorf(ix), y0f = floorf(iy);
            float wx = ix - x0f,   wy = iy - y0f;   // weights from UNclamped floor
            int x0i = (int)x0f, y0i = (int)y0f;
            int x0 = min(max(x0i,     0), ND - 1);
            int x1 = min(max(x0i + 1, 0), ND - 1);
            int y0 = min(max(y0i,     0), NV - 1);
            int y1 = min(max(y0i + 1, 0), NV - 1);

            int   xc  = side ? x1 : x0;             // my x-side
            float wxc = (side ? wx : (1.0f - wx)) * w;

            A[j]  = tbl[((y0 * ND + xc) << 1) + half];   // row y0, my 16B half
            B[j]  = tbl[((y1 * ND + xc) << 1) + half];   // row y1, my 16B half
            WA[j] = wxc * (1.0f - wy);
            WB[j] = wxc * wy;
        }
#pragma unroll
        for (int j = 0; j < 3; ++j) {
            uint ua[4] = {A[j].x, A[j].y, A[j].z, A[j].w};
            uint ub[4] = {B[j].x, B[j].y, B[j].z, B[j].w};
#pragma unroll
            for (int q = 0; q < 4; ++q) {
                acc[2*q]   = fmaf(bf_lo(ua[q]), WA[j], fmaf(bf_lo(ub[q]), WB[j], acc[2*q]));
                acc[2*q+1] = fmaf(bf_hi(ua[q]), WA[j], fmaf(bf_hi(ub[q]), WB[j], acc[2*q+1]));
            }
        }
    }

    // combine x-sides within the quad, then even lanes write their half's channels
#pragma unroll
    for (int k = 0; k < 8; ++k) acc[k] += __shfl_xor(acc[k], 1);
    if (side == 0) {
#pragma unroll
        for (int k = 0; k < 8; ++k)
            atomicAdd(&out[(half * 8 + k) * NP + p], acc[k]);
    }
}

extern "C" void kernel_launch(void* const* d_in, const int* in_sizes, int n_in,
                              void* d_out, int out_size, void* d_ws, size_t ws_size,
                              hipStream_t stream) {
    const float* sino = (const float*)d_in[0];
    const float* grd  = (const float*)d_in[1];
    const float* sq   = (const float*)d_in[2];
    float* out = (float*)d_out;
    ushort* st = (ushort*)d_ws;           // 360*736*16*2B = 8.5 MB

    {
        int n = NV * ND;                  // also covers NC*NP out-zeroing
        k0_transpose<<<(n + 255) / 256, 256, 0, stream>>>(sino, st, out);
    }
    {
        int nblocks = 256 * VS;           // (NP/64) x VS = 2048 blocks
        backproj<<<nblocks, 256, 0, stream>>>(grd, sq, st, out);
    }
}